// Round 1
// baseline (779.010 us; speedup 1.0000x reference)
//
#include <hip/hip_runtime.h>
#include <hip/hip_bf16.h>

#define DEVI __device__ __forceinline__

typedef short bf16x8 __attribute__((ext_vector_type(8)));
typedef float f32x4  __attribute__((ext_vector_type(4)));
typedef unsigned short u16;

using bf16 = __hip_bfloat16;

DEVI bf16x8 ld8(const bf16* p) { return *reinterpret_cast<const bf16x8*>(p); }

DEVI u16 f2bu(float f) {
  union { bf16 h; u16 u; } c; c.h = __float2bfloat16(f); return c.u;
}

#define MFMA16(a, b, c) __builtin_amdgcn_mfma_f32_16x16x32_bf16((a), (b), (c), 0, 0, 0)

// Sizes: B=4, C=256, N=4096 (64x64), 3C=768, groups=32 (8 ch each)

// ---------------- K0: weights fp32 -> bf16 ----------------
__global__ __launch_bounds__(256) void wconv_kernel(const float* __restrict__ wq,
                                                    const float* __restrict__ wp,
                                                    bf16* __restrict__ wqb,
                                                    bf16* __restrict__ wpb) {
  int tid = blockIdx.x * 256 + threadIdx.x;          // 65536 threads, 1 float4 each
  const bool isq = tid < 49152;                      // 768*256/4
  float4 v = isq ? ((const float4*)wq)[tid] : ((const float4*)wp)[tid - 49152];
  alignas(8) bf16 o[4] = { __float2bfloat16(v.x), __float2bfloat16(v.y),
                           __float2bfloat16(v.z), __float2bfloat16(v.w) };
  uint2 pk = *reinterpret_cast<uint2*>(o);
  if (isq) ((uint2*)wqb)[tid] = pk;
  else     ((uint2*)wpb)[tid - 49152] = pk;
}

// ---------------- K1: GroupNorm -> ht[b][n][c] bf16 ----------------
__global__ __launch_bounds__(256) void gn_kernel(const float* __restrict__ x,
                                                 const float* __restrict__ gw,
                                                 const float* __restrict__ gb,
                                                 bf16* __restrict__ ht) {
  const int blk = blockIdx.x;            // b*32 + g
  const int bb = blk >> 5, g = blk & 31;
  const float* xg = x + (size_t)(bb * 256 + g * 8) * 4096;   // 32768 floats

  float s = 0.f, ss = 0.f;
  const float4* x4 = (const float4*)xg;
  for (int i = threadIdx.x; i < 8192; i += 256) {
    float4 v = x4[i];
    s  += v.x + v.y + v.z + v.w;
    ss += v.x * v.x + v.y * v.y + v.z * v.z + v.w * v.w;
  }
  #pragma unroll
  for (int off = 32; off; off >>= 1) {
    s  += __shfl_down(s, off);
    ss += __shfl_down(ss, off);
  }
  __shared__ float red[8];
  int wave = threadIdx.x >> 6;
  if ((threadIdx.x & 63) == 0) { red[wave * 2] = s; red[wave * 2 + 1] = ss; }
  __syncthreads();
  if (threadIdx.x == 0) {
    float S = red[0] + red[2] + red[4] + red[6];
    float SS = red[1] + red[3] + red[5] + red[7];
    float mu = S * (1.f / 32768.f);
    float var = SS * (1.f / 32768.f) - mu * mu;
    red[0] = mu; red[1] = rsqrtf(var + 1e-5f);
  }
  __syncthreads();
  const float mu = red[0], rstd = red[1];

  float gm[8], bt[8];
  #pragma unroll
  for (int j = 0; j < 8; ++j) {
    float wv = gw[g * 8 + j] * rstd;
    gm[j] = wv; bt[j] = gb[g * 8 + j] - mu * wv;
  }
  bf16* hrow = ht + (size_t)bb * 4096 * 256 + g * 8;
  for (int n = threadIdx.x; n < 4096; n += 256) {
    alignas(16) u16 u[8];
    #pragma unroll
    for (int j = 0; j < 8; ++j)
      u[j] = f2bu(xg[j * 4096 + n] * gm[j] + bt[j]);
    *reinterpret_cast<uint4*>(hrow + (size_t)n * 256) = *reinterpret_cast<uint4*>(u);
  }
}

// ---------------- K2: QKV GEMM, D[n][o] = ht[n][c] * W[o][c]^T + bias ----------------
// grid: (bb*6 + ot)*32 + nt  -> 768 blocks, 256 thr (4 waves, 2x2 of 64x64)
__global__ __launch_bounds__(256) void qkv_gemm(const bf16* __restrict__ ht,
                                                const bf16* __restrict__ wq,
                                                const float* __restrict__ qkvb,
                                                bf16* __restrict__ qkvt) {
  int bid = blockIdx.x;
  int nt = bid & 31; int rest = bid >> 5;
  int bb = rest / 6; int ot = rest - bb * 6;
  int tid = threadIdx.x, lane = tid & 63, w = tid >> 6;
  int ln = lane & 15, hi = lane >> 4;
  int wr = w >> 1, wc = w & 1;
  int n_base = nt * 128 + wr * 64, o_base = ot * 128 + wc * 64;
  const bf16* hb = ht + (size_t)bb * 4096 * 256;

  f32x4 acc[4][4] = {};
  for (int cb = 0; cb < 8; ++cb) {
    int c0 = cb * 32 + hi * 8;
    bf16x8 af[4], bfr[4];
    #pragma unroll
    for (int i = 0; i < 4; ++i) af[i]  = ld8(hb + (size_t)(n_base + i * 16 + ln) * 256 + c0);
    #pragma unroll
    for (int j = 0; j < 4; ++j) bfr[j] = ld8(wq + (size_t)(o_base + j * 16 + ln) * 256 + c0);
    #pragma unroll
    for (int i = 0; i < 4; ++i)
      #pragma unroll
      for (int j = 0; j < 4; ++j)
        acc[i][j] = MFMA16(af[i], bfr[j], acc[i][j]);
  }

  bf16* ob = qkvt + (size_t)bb * 4096 * 768;
  #pragma unroll
  for (int j = 0; j < 4; ++j) {
    int o = o_base + j * 16 + ln;
    float bias = qkvb[o];
    #pragma unroll
    for (int i = 0; i < 4; ++i)
      #pragma unroll
      for (int r = 0; r < 4; ++r) {
        int n = n_base + i * 16 + hi * 4 + r;
        ob[(size_t)n * 768 + o] = __float2bfloat16(acc[i][j][r] + bias);
      }
  }
}

// ---------------- K3: transpose V -> vT[c][n] ----------------
// grid: ((bb*64 + ntile)*4 + ctile) -> 1024 blocks
__global__ __launch_bounds__(256) void vtrans_kernel(const bf16* __restrict__ qkvt,
                                                     bf16* __restrict__ vT) {
  int bid = blockIdx.x;
  int ct = bid & 3, ntile = (bid >> 2) & 63, bb = bid >> 8;
  __shared__ bf16 T[64][72];
  int tid = threadIdx.x;
  int i = tid >> 3, j8 = (tid & 7) * 8;
  const bf16* src = qkvt + (size_t)bb * 4096 * 768 + (size_t)(ntile * 64 + i) * 768 + 512 + ct * 64 + j8;
  #pragma unroll
  for (int p = 0; p < 2; ++p) {
    bf16x8 v = ld8(src + (size_t)p * 32 * 768);
    *reinterpret_cast<bf16x8*>(&T[i + p * 32][j8]) = v;
  }
  __syncthreads();
  bf16* dst = vT + (size_t)bb * 256 * 4096 + (size_t)(ct * 64) * 4096 + ntile * 64;
  #pragma unroll
  for (int p = 0; p < 2; ++p) {
    int c = i + p * 32;
    alignas(16) bf16 u[8];
    #pragma unroll
    for (int q = 0; q < 8; ++q) u[q] = T[j8 + q][c];
    *reinterpret_cast<uint4*>(dst + (size_t)c * 4096 + j8) = *reinterpret_cast<uint4*>(u);
  }
}

// ---------------- K4: flash attention ----------------
// grid: bb*64 + qt -> 256 blocks, 4 waves, each wave 16 q-rows
__global__ __launch_bounds__(256) void attn_kernel(const bf16* __restrict__ qkvt,
                                                   const bf16* __restrict__ vT,
                                                   bf16* __restrict__ ho) {
  int bid = blockIdx.x;
  int bb = bid >> 6, qt = bid & 63;
  int tid = threadIdx.x, lane = tid & 63, w = tid >> 6;
  int ln = lane & 15, hi = lane >> 4;
  int n0 = qt * 64 + w * 16;
  const bf16* qb = qkvt + (size_t)bb * 4096 * 768;
  const bf16* vb = vT + (size_t)bb * 256 * 4096;

  // Q fragments in registers (16 rows x 256 c)
  bf16x8 aq[8];
  #pragma unroll
  for (int cb = 0; cb < 8; ++cb)
    aq[cb] = ld8(qb + (size_t)(n0 + ln) * 768 + cb * 32 + hi * 8);

  f32x4 acc[16] = {};
  float m_run[4], l_run[4];
  #pragma unroll
  for (int r = 0; r < 4; ++r) { m_run[r] = -3.0e38f; l_run[r] = 0.f; }

  __shared__ bf16 Pl[4][16][72];

  for (int t = 0; t < 64; ++t) {
    int m0 = t * 64;
    // ---- S = (Q K^T) / 16 ----
    f32x4 s[4] = {};
    #pragma unroll
    for (int mf = 0; mf < 4; ++mf) {
      #pragma unroll
      for (int cb = 0; cb < 8; ++cb) {
        bf16x8 bk = ld8(qb + (size_t)(m0 + mf * 16 + ln) * 768 + 256 + cb * 32 + hi * 8);
        s[mf] = MFMA16(aq[cb], bk, s[mf]);
      }
    }
    #pragma unroll
    for (int mf = 0; mf < 4; ++mf) s[mf] = s[mf] * 0.0625f;

    // ---- online softmax (rows n = n0 + hi*4 + r; reduce across 16-lane group) ----
    float alpha[4], rowsum[4];
    #pragma unroll
    for (int r = 0; r < 4; ++r) {
      float m = fmaxf(fmaxf(s[0][r], s[1][r]), fmaxf(s[2][r], s[3][r]));
      #pragma unroll
      for (int off = 1; off < 16; off <<= 1) m = fmaxf(m, __shfl_xor(m, off));
      float mnew = fmaxf(m_run[r], m);
      alpha[r] = __expf(m_run[r] - mnew);
      m_run[r] = mnew;
    }
    #pragma unroll
    for (int mf = 0; mf < 4; ++mf)
      #pragma unroll
      for (int r = 0; r < 4; ++r)
        s[mf][r] = __expf(s[mf][r] - m_run[r]);
    #pragma unroll
    for (int r = 0; r < 4; ++r) {
      float rs = s[0][r] + s[1][r] + s[2][r] + s[3][r];
      #pragma unroll
      for (int off = 1; off < 16; off <<= 1) rs += __shfl_xor(rs, off);
      l_run[r] = l_run[r] * alpha[r] + rs;
    }
    f32x4 av = { alpha[0], alpha[1], alpha[2], alpha[3] };
    #pragma unroll
    for (int cf = 0; cf < 16; ++cf) acc[cf] = acc[cf] * av;

    // ---- P -> LDS (per-wave region, no barrier needed) ----
    #pragma unroll
    for (int mf = 0; mf < 4; ++mf)
      #pragma unroll
      for (int r = 0; r < 4; ++r)
        Pl[w][hi * 4 + r][mf * 16 + ln] = __float2bfloat16(s[mf][r]);

    // ---- O += P V ----
    #pragma unroll
    for (int ms = 0; ms < 2; ++ms) {
      bf16x8 pa = ld8(&Pl[w][ln][ms * 32 + hi * 8]);
      #pragma unroll
      for (int cf = 0; cf < 16; ++cf) {
        bf16x8 bv = ld8(vb + (size_t)(cf * 16 + ln) * 4096 + m0 + ms * 32 + hi * 8);
        acc[cf] = MFMA16(pa, bv, acc[cf]);
      }
    }
  }

  // ---- epilogue: ho[b][n][c] = acc / l ----
  bf16* hb = ho + (size_t)bb * 4096 * 256;
  #pragma unroll
  for (int r = 0; r < 4; ++r) {
    float inv = 1.f / l_run[r];
    int n = n0 + hi * 4 + r;
    #pragma unroll
    for (int cf = 0; cf < 16; ++cf)
      hb[(size_t)n * 256 + cf * 16 + ln] = __float2bfloat16(acc[cf][r] * inv);
  }
}

// ---------------- K5: proj GEMM + residual, D[o][n] = W[o][c] * ho[n][c]^T ----------------
// grid: (bb*2 + ot)*32 + nt -> 256 blocks
__global__ __launch_bounds__(256) void proj_gemm(const bf16* __restrict__ ho,
                                                 const bf16* __restrict__ wp,
                                                 const float* __restrict__ pb,
                                                 const float* __restrict__ x,
                                                 float* __restrict__ out) {
  int bid = blockIdx.x;
  int nt = bid & 31; int rest = bid >> 5;
  int ot = rest & 1; int bb = rest >> 1;
  int tid = threadIdx.x, lane = tid & 63, w = tid >> 6;
  int ln = lane & 15, hi = lane >> 4;
  int wr = w >> 1, wc = w & 1;
  int o_base = ot * 128 + wr * 64, n_base = nt * 128 + wc * 64;
  const bf16* hb = ho + (size_t)bb * 4096 * 256;

  f32x4 acc[4][4] = {};
  for (int cb = 0; cb < 8; ++cb) {
    int c0 = cb * 32 + hi * 8;
    bf16x8 af[4], bfr[4];
    #pragma unroll
    for (int i = 0; i < 4; ++i) af[i]  = ld8(wp + (size_t)(o_base + i * 16 + ln) * 256 + c0);
    #pragma unroll
    for (int j = 0; j < 4; ++j) bfr[j] = ld8(hb + (size_t)(n_base + j * 16 + ln) * 256 + c0);
    #pragma unroll
    for (int i = 0; i < 4; ++i)
      #pragma unroll
      for (int j = 0; j < 4; ++j)
        acc[i][j] = MFMA16(af[i], bfr[j], acc[i][j]);
  }

  const float* xb = x + (size_t)bb * 256 * 4096;
  float* ob = out + (size_t)bb * 256 * 4096;
  #pragma unroll
  for (int i = 0; i < 4; ++i)
    #pragma unroll
    for (int r = 0; r < 4; ++r) {
      int o = o_base + i * 16 + hi * 4 + r;
      float bias = pb[o];
      #pragma unroll
      for (int j = 0; j < 4; ++j) {
        int n = n_base + j * 16 + ln;
        size_t idx = (size_t)o * 4096 + n;
        ob[idx] = xb[idx] + bias + acc[i][j][r];
      }
    }
}

extern "C" void kernel_launch(void* const* d_in, const int* in_sizes, int n_in,
                              void* d_out, int out_size, void* d_ws, size_t ws_size,
                              hipStream_t stream) {
  const float* x   = (const float*)d_in[0];
  const float* gnw = (const float*)d_in[1];
  const float* gnb = (const float*)d_in[2];
  const float* qw  = (const float*)d_in[3];
  const float* qb  = (const float*)d_in[4];
  const float* pw  = (const float*)d_in[5];
  const float* pb  = (const float*)d_in[6];
  float* out = (float*)d_out;

  char* ws = (char*)d_ws;
  bf16* ht   = (bf16*)(ws);                               // [4][4096][256]   8 MB
  bf16* qkvt = (bf16*)(ws + ((size_t)8 << 20));           // [4][4096][768]  24 MB
  bf16* vT   = (bf16*)(ws + ((size_t)32 << 20));          // [4][256][4096]   8 MB
  bf16* ho   = (bf16*)(ws + ((size_t)40 << 20));          // [4][4096][256]   8 MB
  bf16* wqb  = (bf16*)(ws + ((size_t)48 << 20));          // [768][256]
  bf16* wpb  = (bf16*)(ws + ((size_t)48 << 20) + 768 * 256 * 2); // [256][256]

  wconv_kernel<<<dim3(256), dim3(256), 0, stream>>>(qw, pw, wqb, wpb);
  gn_kernel<<<dim3(128), dim3(256), 0, stream>>>(x, gnw, gnb, ht);
  qkv_gemm<<<dim3(768), dim3(256), 0, stream>>>(ht, wqb, qb, qkvt);
  vtrans_kernel<<<dim3(1024), dim3(256), 0, stream>>>(qkvt, vT);
  attn_kernel<<<dim3(256), dim3(256), 0, stream>>>(qkvt, vT, ho);
  proj_gemm<<<dim3(256), dim3(256), 0, stream>>>(ho, wpb, pb, x, out);
}

// Round 2
// 600.271 us; speedup vs baseline: 1.2978x; 1.2978x over previous
//
#include <hip/hip_runtime.h>
#include <hip/hip_bf16.h>

#define DEVI __device__ __forceinline__

typedef short bf16x8 __attribute__((ext_vector_type(8)));
typedef float f32x4  __attribute__((ext_vector_type(4)));
typedef unsigned short u16;

using bf16 = __hip_bfloat16;

DEVI bf16x8 ld8(const bf16* p) { return *reinterpret_cast<const bf16x8*>(p); }

DEVI u16 f2bu(float f) {
  union { bf16 h; u16 u; } c; c.h = __float2bfloat16(f); return c.u;
}
DEVI float b2f(u16 u) {
  union { float f; unsigned int i; } c; c.i = ((unsigned int)u) << 16; return c.f;
}

#define MFMA16(a, b, c) __builtin_amdgcn_mfma_f32_16x16x32_bf16((a), (b), (c), 0, 0, 0)

// Sizes: B=4, C=256, N=4096 (64x64), 3C=768, groups=32 (8 ch each)

// ---------------- K0: weights fp32 -> bf16 ----------------
__global__ __launch_bounds__(256) void wconv_kernel(const float* __restrict__ wq,
                                                    const float* __restrict__ wp,
                                                    bf16* __restrict__ wqb,
                                                    bf16* __restrict__ wpb) {
  int tid = blockIdx.x * 256 + threadIdx.x;
  const bool isq = tid < 49152;
  float4 v = isq ? ((const float4*)wq)[tid] : ((const float4*)wp)[tid - 49152];
  alignas(8) bf16 o[4] = { __float2bfloat16(v.x), __float2bfloat16(v.y),
                           __float2bfloat16(v.z), __float2bfloat16(v.w) };
  uint2 pk = *reinterpret_cast<uint2*>(o);
  if (isq) ((uint2*)wqb)[tid] = pk;
  else     ((uint2*)wpb)[tid - 49152] = pk;
}

// ---------------- K1: GroupNorm -> ht[b][n][c] bf16 ----------------
__global__ __launch_bounds__(256) void gn_kernel(const float* __restrict__ x,
                                                 const float* __restrict__ gw,
                                                 const float* __restrict__ gb,
                                                 bf16* __restrict__ ht) {
  const int blk = blockIdx.x;            // b*32 + g
  const int bb = blk >> 5, g = blk & 31;
  const float* xg = x + (size_t)(bb * 256 + g * 8) * 4096;

  float s = 0.f, ss = 0.f;
  const float4* x4 = (const float4*)xg;
  for (int i = threadIdx.x; i < 8192; i += 256) {
    float4 v = x4[i];
    s  += v.x + v.y + v.z + v.w;
    ss += v.x * v.x + v.y * v.y + v.z * v.z + v.w * v.w;
  }
  #pragma unroll
  for (int off = 32; off; off >>= 1) {
    s  += __shfl_down(s, off);
    ss += __shfl_down(ss, off);
  }
  __shared__ float red[8];
  int wave = threadIdx.x >> 6;
  if ((threadIdx.x & 63) == 0) { red[wave * 2] = s; red[wave * 2 + 1] = ss; }
  __syncthreads();
  if (threadIdx.x == 0) {
    float S = red[0] + red[2] + red[4] + red[6];
    float SS = red[1] + red[3] + red[5] + red[7];
    float mu = S * (1.f / 32768.f);
    float var = SS * (1.f / 32768.f) - mu * mu;
    red[0] = mu; red[1] = rsqrtf(var + 1e-5f);
  }
  __syncthreads();
  const float mu = red[0], rstd = red[1];

  float gm[8], bt[8];
  #pragma unroll
  for (int j = 0; j < 8; ++j) {
    float wv = gw[g * 8 + j] * rstd;
    gm[j] = wv; bt[j] = gb[g * 8 + j] - mu * wv;
  }
  bf16* hrow = ht + (size_t)bb * 4096 * 256 + g * 8;
  for (int n = threadIdx.x; n < 4096; n += 256) {
    alignas(16) u16 u[8];
    #pragma unroll
    for (int j = 0; j < 8; ++j)
      u[j] = f2bu(xg[j * 4096 + n] * gm[j] + bt[j]);
    *reinterpret_cast<uint4*>(hrow + (size_t)n * 256) = *reinterpret_cast<uint4*>(u);
  }
}

// ---------------- K2: QKV GEMM, qkvt[n][o] = ht[n][c]*W[o][c]^T + bias; Q pre-scaled 1/16 ----------------
__global__ __launch_bounds__(256) void qkv_gemm(const bf16* __restrict__ ht,
                                                const bf16* __restrict__ wq,
                                                const float* __restrict__ qkvb,
                                                bf16* __restrict__ qkvt) {
  int bid = blockIdx.x;
  int nt = bid & 31; int rest = bid >> 5;
  int bb = rest / 6; int ot = rest - bb * 6;
  int tid = threadIdx.x, lane = tid & 63, w = tid >> 6;
  int ln = lane & 15, hi = lane >> 4;
  int wr = w >> 1, wc = w & 1;
  int n_base = nt * 128 + wr * 64, o_base = ot * 128 + wc * 64;
  const bf16* hb = ht + (size_t)bb * 4096 * 256;

  f32x4 acc[4][4] = {};
  for (int cb = 0; cb < 8; ++cb) {
    int c0 = cb * 32 + hi * 8;
    bf16x8 af[4], bfr[4];
    #pragma unroll
    for (int i = 0; i < 4; ++i) af[i]  = ld8(hb + (size_t)(n_base + i * 16 + ln) * 256 + c0);
    #pragma unroll
    for (int j = 0; j < 4; ++j) bfr[j] = ld8(wq + (size_t)(o_base + j * 16 + ln) * 256 + c0);
    #pragma unroll
    for (int i = 0; i < 4; ++i)
      #pragma unroll
      for (int j = 0; j < 4; ++j)
        acc[i][j] = MFMA16(af[i], bfr[j], acc[i][j]);
  }

  const float sc = (ot < 2) ? 0.0625f : 1.0f;   // fold the 1/sqrt(C)=1/16 into Q
  bf16* ob = qkvt + (size_t)bb * 4096 * 768;
  #pragma unroll
  for (int j = 0; j < 4; ++j) {
    int o = o_base + j * 16 + ln;
    float bias = qkvb[o];
    #pragma unroll
    for (int i = 0; i < 4; ++i)
      #pragma unroll
      for (int r = 0; r < 4; ++r) {
        int n = n_base + i * 16 + hi * 4 + r;
        ob[(size_t)n * 768 + o] = __float2bfloat16((acc[i][j][r] + bias) * sc);
      }
  }
}

// ---------------- K3: transpose V -> vT[c][n] ----------------
__global__ __launch_bounds__(256) void vtrans_kernel(const bf16* __restrict__ qkvt,
                                                     bf16* __restrict__ vT) {
  int bid = blockIdx.x;
  int ct = bid & 3, ntile = (bid >> 2) & 63, bb = bid >> 8;
  __shared__ bf16 T[64][72];
  int tid = threadIdx.x;
  int i = tid >> 3, j8 = (tid & 7) * 8;
  const bf16* src = qkvt + (size_t)bb * 4096 * 768 + (size_t)(ntile * 64 + i) * 768 + 512 + ct * 64 + j8;
  #pragma unroll
  for (int p = 0; p < 2; ++p) {
    bf16x8 v = ld8(src + (size_t)p * 32 * 768);
    *reinterpret_cast<bf16x8*>(&T[i + p * 32][j8]) = v;
  }
  __syncthreads();
  bf16* dst = vT + (size_t)bb * 256 * 4096 + (size_t)(ct * 64) * 4096 + ntile * 64;
  #pragma unroll
  for (int p = 0; p < 2; ++p) {
    int c = i + p * 32;
    alignas(16) bf16 u[8];
    #pragma unroll
    for (int q = 0; q < 8; ++q) u[q] = T[j8 + q][c];
    *reinterpret_cast<uint4*>(dst + (size_t)c * 4096 + j8) = *reinterpret_cast<uint4*>(u);
  }
}

// ---------------- K4: flash attention, split-KV ----------------
// grid 512: logical L = bb(2b) | qt(5b) | sp(2b); 4 waves, wave owns 32 q-rows.
__global__ __launch_bounds__(256, 2) void attn_kernel(const bf16* __restrict__ qkvt,
                                                      const bf16* __restrict__ vT,
                                                      bf16* __restrict__ Opart,
                                                      float* __restrict__ ml) {
  int phys = blockIdx.x;
  int L = (phys & 7) * 64 + (phys >> 3);        // XCD swizzle (512 % 8 == 0, bijective)
  int bb = L >> 7, qt = (L >> 2) & 31, sp = L & 3;
  int tid = threadIdx.x, lane = tid & 63, w = tid >> 6;
  int ln = lane & 15, hi = lane >> 4;
  int n0 = qt * 128 + w * 32;
  const bf16* qb = qkvt + (size_t)bb * 4096 * 768;
  const bf16* vb = vT + (size_t)bb * 256 * 4096;

  // Q fragments in registers: 32 rows x 256 ch (Q pre-scaled by 1/16)
  bf16x8 aq[2][8];
  #pragma unroll
  for (int mt = 0; mt < 2; ++mt)
    #pragma unroll
    for (int cb = 0; cb < 8; ++cb)
      aq[mt][cb] = ld8(qb + (size_t)(n0 + mt * 16 + ln) * 768 + cb * 32 + hi * 8);

  f32x4 acc[2][16] = {};
  float m_run[2][4], lsum[2][4];
  #pragma unroll
  for (int mt = 0; mt < 2; ++mt)
    #pragma unroll
    for (int r = 0; r < 4; ++r) { m_run[mt][r] = -3.0e38f; lsum[mt][r] = 0.f; }

  // per-wave P tile [32 rows][64 cols] bf16, XOR-swizzled (row stride 128B)
  __shared__ bf16 Pl[4][32][64];
  char* Plb = (char*)&Pl[w][0][0];

  for (int t = 0; t < 16; ++t) {
    int m0 = sp * 1024 + t * 64;
    // ---- S = Q K^T (Q already has the 1/16 scale) ----
    f32x4 s[2][4] = {};
    #pragma unroll
    for (int kt = 0; kt < 4; ++kt)
      #pragma unroll
      for (int cb = 0; cb < 8; ++cb) {
        bf16x8 bk = ld8(qb + (size_t)(m0 + kt * 16 + ln) * 768 + 256 + cb * 32 + hi * 8);
        s[0][kt] = MFMA16(aq[0][cb], bk, s[0][kt]);
        s[1][kt] = MFMA16(aq[1][cb], bk, s[1][kt]);
      }

    // ---- tile row max (reduce over 16 lanes of the k-col dim) ----
    float mloc[2][4];
    #pragma unroll
    for (int mt = 0; mt < 2; ++mt)
      #pragma unroll
      for (int r = 0; r < 4; ++r) {
        float m = fmaxf(fmaxf(s[mt][0][r], s[mt][1][r]), fmaxf(s[mt][2][r], s[mt][3][r]));
        #pragma unroll
        for (int off = 1; off < 16; off <<= 1) m = fmaxf(m, __shfl_xor(m, off));
        mloc[mt][r] = m;
      }

    // ---- defer-max: rescale acc only when max grows by > 8 ----
    int need = 0;
    #pragma unroll
    for (int mt = 0; mt < 2; ++mt)
      #pragma unroll
      for (int r = 0; r < 4; ++r)
        need |= (mloc[mt][r] > m_run[mt][r] + 8.f) ? 1 : 0;
    if (__any(need)) {
      #pragma unroll
      for (int mt = 0; mt < 2; ++mt) {
        f32x4 al;
        #pragma unroll
        for (int r = 0; r < 4; ++r) {
          float mnew = fmaxf(m_run[mt][r], mloc[mt][r]);
          al[r] = __expf(m_run[mt][r] - mnew);
          m_run[mt][r] = mnew;
          lsum[mt][r] *= al[r];
        }
        #pragma unroll
        for (int cf = 0; cf < 16; ++cf) acc[mt][cf] = acc[mt][cf] * al;
      }
    }

    // ---- P = exp(S - m); per-lane partial l ----
    #pragma unroll
    for (int mt = 0; mt < 2; ++mt) {
      #pragma unroll
      for (int kt = 0; kt < 4; ++kt)
        #pragma unroll
        for (int r = 0; r < 4; ++r)
          s[mt][kt][r] = __expf(s[mt][kt][r] - m_run[mt][r]);
      #pragma unroll
      for (int r = 0; r < 4; ++r)
        lsum[mt][r] += s[mt][0][r] + s[mt][1][r] + s[mt][2][r] + s[mt][3][r];
    }

    // ---- P -> LDS (per-wave tile, swizzled) ----
    #pragma unroll
    for (int mt = 0; mt < 2; ++mt)
      #pragma unroll
      for (int kt = 0; kt < 4; ++kt)
        #pragma unroll
        for (int r = 0; r < 4; ++r) {
          int row = mt * 16 + hi * 4 + r;
          int byte = (row * 128 + (kt * 16 + ln) * 2) ^ ((row & 7) << 4);
          *(bf16*)(Plb + byte) = __float2bfloat16(s[mt][kt][r]);
        }

    // ---- O += P V ----
    #pragma unroll
    for (int ms = 0; ms < 2; ++ms) {
      int r0 = ln, r1 = 16 + ln;
      bf16x8 pa0 = *(const bf16x8*)(Plb + ((r0 * 128 + ms * 64 + hi * 16) ^ ((r0 & 7) << 4)));
      bf16x8 pa1 = *(const bf16x8*)(Plb + ((r1 * 128 + ms * 64 + hi * 16) ^ ((r1 & 7) << 4)));
      #pragma unroll
      for (int cf = 0; cf < 16; ++cf) {
        bf16x8 bv = ld8(vb + (size_t)(cf * 16 + ln) * 4096 + m0 + ms * 32 + hi * 8);
        acc[0][cf] = MFMA16(pa0, bv, acc[0][cf]);
        acc[1][cf] = MFMA16(pa1, bv, acc[1][cf]);
      }
    }
  }

  // ---- epilogue: reduce l, write (m,l) + unnormalized partial O ----
  #pragma unroll
  for (int mt = 0; mt < 2; ++mt)
    #pragma unroll
    for (int r = 0; r < 4; ++r) {
      float v = lsum[mt][r];
      #pragma unroll
      for (int off = 1; off < 16; off <<= 1) v += __shfl_xor(v, off);
      lsum[mt][r] = v;
    }
  size_t rb = (size_t)sp * 16384 + (size_t)bb * 4096;
  if (ln == 0) {
    #pragma unroll
    for (int mt = 0; mt < 2; ++mt)
      #pragma unroll
      for (int r = 0; r < 4; ++r) {
        int n = n0 + mt * 16 + hi * 4 + r;
        ml[(rb + n) * 2]     = m_run[mt][r];
        ml[(rb + n) * 2 + 1] = lsum[mt][r];
      }
  }
  bf16* ob = Opart + rb * 256;
  #pragma unroll
  for (int mt = 0; mt < 2; ++mt)
    #pragma unroll
    for (int r = 0; r < 4; ++r) {
      int n = n0 + mt * 16 + hi * 4 + r;
      #pragma unroll
      for (int cf = 0; cf < 16; ++cf)
        ob[(size_t)n * 256 + cf * 16 + ln] = __float2bfloat16(acc[mt][cf][r]);
    }
}

// ---------------- K4b: combine split-KV partials -> ho[b][n][c] ----------------
__global__ __launch_bounds__(256) void combine_kernel(const bf16* __restrict__ Opart,
                                                      const float* __restrict__ ml,
                                                      bf16* __restrict__ ho) {
  int rowg = blockIdx.x * 32 + (threadIdx.x >> 3);   // b*4096 + n
  int cg = (threadIdx.x & 7) * 32;
  float msp[4]; float M = -3.0e38f;
  #pragma unroll
  for (int sp = 0; sp < 4; ++sp) {
    msp[sp] = ml[((size_t)sp * 16384 + rowg) * 2];
    M = fmaxf(M, msp[sp]);
  }
  float acc[32];
  #pragma unroll
  for (int j = 0; j < 32; ++j) acc[j] = 0.f;
  float Ltot = 0.f;
  #pragma unroll
  for (int sp = 0; sp < 4; ++sp) {
    float sc = __expf(msp[sp] - M);
    Ltot += ml[((size_t)sp * 16384 + rowg) * 2 + 1] * sc;
    const bf16* p = Opart + ((size_t)sp * 16384 + rowg) * 256 + cg;
    #pragma unroll
    for (int v = 0; v < 4; ++v) {
      bf16x8 u = ld8(p + v * 8);
      #pragma unroll
      for (int j = 0; j < 8; ++j) acc[v * 8 + j] += sc * b2f((u16)u[j]);
    }
  }
  float inv = 1.f / Ltot;
  bf16* o = ho + (size_t)rowg * 256 + cg;
  #pragma unroll
  for (int v = 0; v < 4; ++v) {
    alignas(16) u16 u[8];
    #pragma unroll
    for (int j = 0; j < 8; ++j) u[j] = f2bu(acc[v * 8 + j] * inv);
    *reinterpret_cast<uint4*>(o + v * 8) = *reinterpret_cast<uint4*>(u);
  }
}

// ---------------- K5: proj GEMM + residual ----------------
__global__ __launch_bounds__(256) void proj_gemm(const bf16* __restrict__ ho,
                                                 const bf16* __restrict__ wp,
                                                 const float* __restrict__ pb,
                                                 const float* __restrict__ x,
                                                 float* __restrict__ out) {
  int bid = blockIdx.x;
  int nt = bid & 31; int rest = bid >> 5;
  int ot = rest & 1; int bb = rest >> 1;
  int tid = threadIdx.x, lane = tid & 63, w = tid >> 6;
  int ln = lane & 15, hi = lane >> 4;
  int wr = w >> 1, wc = w & 1;
  int o_base = ot * 128 + wr * 64, n_base = nt * 128 + wc * 64;
  const bf16* hb = ho + (size_t)bb * 4096 * 256;

  f32x4 acc[4][4] = {};
  for (int cb = 0; cb < 8; ++cb) {
    int c0 = cb * 32 + hi * 8;
    bf16x8 af[4], bfr[4];
    #pragma unroll
    for (int i = 0; i < 4; ++i) af[i]  = ld8(wp + (size_t)(o_base + i * 16 + ln) * 256 + c0);
    #pragma unroll
    for (int j = 0; j < 4; ++j) bfr[j] = ld8(hb + (size_t)(n_base + j * 16 + ln) * 256 + c0);
    #pragma unroll
    for (int i = 0; i < 4; ++i)
      #pragma unroll
      for (int j = 0; j < 4; ++j)
        acc[i][j] = MFMA16(af[i], bfr[j], acc[i][j]);
  }

  const float* xb = x + (size_t)bb * 256 * 4096;
  float* ob = out + (size_t)bb * 256 * 4096;
  #pragma unroll
  for (int i = 0; i < 4; ++i)
    #pragma unroll
    for (int r = 0; r < 4; ++r) {
      int o = o_base + i * 16 + hi * 4 + r;
      float bias = pb[o];
      #pragma unroll
      for (int j = 0; j < 4; ++j) {
        int n = n_base + j * 16 + ln;
        size_t idx = (size_t)o * 4096 + n;
        ob[idx] = xb[idx] + bias + acc[i][j][r];
      }
    }
}

extern "C" void kernel_launch(void* const* d_in, const int* in_sizes, int n_in,
                              void* d_out, int out_size, void* d_ws, size_t ws_size,
                              hipStream_t stream) {
  const float* x   = (const float*)d_in[0];
  const float* gnw = (const float*)d_in[1];
  const float* gnb = (const float*)d_in[2];
  const float* qw  = (const float*)d_in[3];
  const float* qb  = (const float*)d_in[4];
  const float* pw  = (const float*)d_in[5];
  const float* pb  = (const float*)d_in[6];
  float* out = (float*)d_out;

  char* ws = (char*)d_ws;
  bf16* ht    = (bf16*)(ws);                               // [4][4096][256]    0..8 MB
  bf16* qkvt  = (bf16*)(ws + ((size_t)8 << 20));           // [4][4096][768]    8..32 MB
  bf16* vT    = (bf16*)(ws + ((size_t)32 << 20));          // [4][256][4096]   32..40 MB
  bf16* ho    = (bf16*)(ws + ((size_t)40 << 20));          // [4][4096][256]   40..48 MB
  bf16* wqb   = (bf16*)(ws + ((size_t)48 << 20));          // [768][256]
  bf16* wpb   = (bf16*)(ws + ((size_t)48 << 20) + 768 * 256 * 2);
  float* ml   = (float*)(ws + ((size_t)48 << 20) + ((size_t)1 << 19)); // [4][16384][2] f32, 512 KB
  bf16* Opart = (bf16*)(ws + ((size_t)49 << 20));          // [4][16384][256] bf16, 49..81 MB

  wconv_kernel<<<dim3(256), dim3(256), 0, stream>>>(qw, pw, wqb, wpb);
  gn_kernel<<<dim3(128), dim3(256), 0, stream>>>(x, gnw, gnb, ht);
  qkv_gemm<<<dim3(768), dim3(256), 0, stream>>>(ht, wqb, qb, qkvt);
  vtrans_kernel<<<dim3(1024), dim3(256), 0, stream>>>(qkvt, vT);
  attn_kernel<<<dim3(512), dim3(256), 0, stream>>>(qkvt, vT, Opart, ml);
  combine_kernel<<<dim3(512), dim3(256), 0, stream>>>(Opart, ml, ho);
  proj_gemm<<<dim3(256), dim3(256), 0, stream>>>(ho, wpb, pb, x, out);
}